// Round 1
// baseline (229.256 us; speedup 1.0000x reference)
//
#include <hip/hip_runtime.h>
#include <math.h>

// SDFNet: conv1x1(1->8) -> 16x (h += minpool3(h)) -> conv3x3(8->32) -> relu -> conv1x1(32->1)
//
// Factorization: erosion iterations act per-channel on affine maps of x.
//   w0[c] > 0:  h_c after 16 iters = w0[c]*P16(x) + b0[c]*2^16   (P = min-iterate)
//   w0[c] < 0:  h_c = w0[c]*M16(x) + b0[c]*2^16, and M16(x) = -P16(-x)
// So we only ever run the MIN iterate, on two planes per image: P=iter(x), Q=iter(-x),
// and fold w0/b0 into effective head weights WP/WQ/BIAS (prep_kernel).
// Head: out = b2 + sum_oc relu(BIAS[oc] + sum_k WP[oc,k]*P_nbhd + WQ[oc,k]*Q_nbhd) * w2[oc]

#define N_PIX (512*512)
constexpr int BW = 80;   // 64 output tile + 2*8 halo

// ---------------------------------------------------------------- prep
__global__ void prep_kernel(const float* __restrict__ w0, const float* __restrict__ b0,
                            const float* __restrict__ w1, const float* __restrict__ b1,
                            float* __restrict__ W)
{
    int tid = threadIdx.x;
    if (tid < 288) {
        int oc = tid / 9, k = tid - oc*9;
        float wp = 0.f, wq = 0.f;
        for (int ic = 0; ic < 8; ++ic) {
            float a = w0[ic];
            float w = w1[oc*72 + ic*9 + k];
            if (a > 0.f) wp += w * a;
            else         wq += w * (-a);   // coeff on Q = -w0 = |w0|
        }
        W[tid]       = wp;   // WP[0..287]
        W[288 + tid] = wq;   // WQ[288..575]
        if (k == 0) {
            float bias = b1[oc];
            for (int ic = 0; ic < 8; ++ic) {
                float srow = 0.f;
                for (int kk = 0; kk < 9; ++kk) srow += w1[oc*72 + ic*9 + kk];
                bias += 65536.0f * b0[ic] * srow;   // bias doubles each of 16 iters
            }
            W[576 + oc] = bias;  // BIAS[576..607]
        }
    }
}

// ---------------------------------------------------------------- erosion (8 fused steps)
// grid (8,8,16): x-tile, y-tile, plane. planes 0..7 = P(x) per image, 8..15 = Q(-x).
// Double-buffered 80x80 LDS tile; interior [1,79) recomputed each step; junk ring grows
// 1/step so after 8 steps center [8,72) is exact -> the 64x64 output.
__global__ __launch_bounds__(256) void erode8_kernel(
    const float* __restrict__ src, float* __restrict__ dst, int first_pass)
{
    __shared__ __align__(16) float lds[8 + 2*BW*BW + 8];  // front/back pads for benign OOR reads
    float* buf0 = lds + 8;
    float* buf1 = buf0 + BW*BW;
    const int tid   = threadIdx.x;
    const int plane = blockIdx.z;
    const int tx0 = blockIdx.x*64 - 8;
    const int ty0 = blockIdx.y*64 - 8;

    const float* sp;
    float sgn = 1.0f;
    if (first_pass) { sp = src + (plane & 7)*N_PIX; if (plane >= 8) sgn = -1.0f; }
    else            { sp = src + plane*N_PIX; }

    // stage 80x80 (+inf sentinel outside image = min-identity); init BOTH buffers so
    // stale rings are well-defined
    for (int i = tid; i < BW*BW; i += 256) {
        int r = i / BW;
        int c = i - r*BW;
        int gy = ty0 + r, gx = tx0 + c;
        float v = __builtin_inff();
        if ((unsigned)gy < 512u && (unsigned)gx < 512u) v = sgn * sp[gy*512 + gx];
        buf0[i] = v; buf1[i] = v;
    }
    __syncthreads();

    float* cur = buf0; float* nxt = buf1;
    for (int s = 0; s < 8; ++s) {
        // 39 row-pairs x 20 col-quads = 780 units; each unit: 2 rows x 4 cols output
        for (int u = tid; u < 780; u += 256) {
            int rp = u / 20;
            int c4 = u - rp*20;
            int r  = 1 + rp*2;        // output rows r, r+1 in [1,78]
            int cb = c4*4;            // output cols cb..cb+3 (cols 0 and 79 masked off)
            const float* r0 = cur + (r-1)*BW + cb;
            const float* r1 = r0 + BW;
            const float* r2 = r1 + BW;
            const float* r3 = r2 + BW;
            float4 m0 = *(const float4*)r0; float l0 = r0[-1], e0 = r0[4];
            float4 m1 = *(const float4*)r1; float l1 = r1[-1], e1 = r1[4];
            float4 m2 = *(const float4*)r2; float l2 = r2[-1], e2 = r2[4];
            float4 m3 = *(const float4*)r3; float l3 = r3[-1], e3 = r3[4];

            // shared middle pair (rows r, r+1)
            float t0 = fminf(m1.x, m2.x), t1 = fminf(m1.y, m2.y);
            float t2 = fminf(m1.z, m2.z), t3 = fminf(m1.w, m2.w);
            float tl = fminf(l1, l2),     te = fminf(e1, e2);
            // vertical mins for output row r (rows r-1..r+1)
            float vt0 = fminf(t0, m0.x), vt1 = fminf(t1, m0.y);
            float vt2 = fminf(t2, m0.z), vt3 = fminf(t3, m0.w);
            float vtl = fminf(tl, l0),   vte = fminf(te, e0);
            // vertical mins for output row r+1 (rows r..r+2)
            float vb0 = fminf(t0, m3.x), vb1 = fminf(t1, m3.y);
            float vb2 = fminf(t2, m3.z), vb3 = fminf(t3, m3.w);
            float vbl = fminf(tl, l3),   vbe = fminf(te, e3);
            // horizontal 3-mins + add
            float oa0 = m1.x + fminf(fminf(vtl, vt0), vt1);
            float oa1 = m1.y + fminf(fminf(vt0, vt1), vt2);
            float oa2 = m1.z + fminf(fminf(vt1, vt2), vt3);
            float oa3 = m1.w + fminf(fminf(vt2, vt3), vte);
            float ob0 = m2.x + fminf(fminf(vbl, vb0), vb1);
            float ob1 = m2.y + fminf(fminf(vb0, vb1), vb2);
            float ob2 = m2.z + fminf(fminf(vb1, vb2), vb3);
            float ob3 = m2.w + fminf(fminf(vb2, vb3), vbe);

            float* wa = nxt + r*BW + cb;
            float* wb = wa + BW;
            if (c4 != 0 && c4 != 19) {
                *(float4*)wa = make_float4(oa0, oa1, oa2, oa3);
                *(float4*)wb = make_float4(ob0, ob1, ob2, ob3);
            } else if (c4 == 0) {       // col 0 excluded
                wa[1] = oa1; wa[2] = oa2; wa[3] = oa3;
                wb[1] = ob1; wb[2] = ob2; wb[3] = ob3;
            } else {                    // c4 == 19: col 79 excluded
                wa[0] = oa0; wa[1] = oa1; wa[2] = oa2;
                wb[0] = ob0; wb[1] = ob1; wb[2] = ob2;
            }
        }
        __syncthreads();
        float* tmp = cur; cur = nxt; nxt = tmp;
    }

    // after 8 (even) steps result is back in buf0 == cur; write central 64x64
    for (int i = tid; i < 64*64; i += 256) {
        int r = i >> 6, c = i & 63;
        dst[plane*N_PIX + (ty0 + 8 + r)*512 + (tx0 + 8 + c)] = cur[(r+8)*BW + (c+8)];
    }
}

// ---------------------------------------------------------------- head (3x3 conv 2ch->32, relu, dot w2)
// one thread = 4 horizontal pixels; weights are wave-uniform -> scalar loads
__global__ __launch_bounds__(256) void head_kernel(
    const float* __restrict__ A, const float* __restrict__ W,
    const float* __restrict__ w2, const float* __restrict__ b2,
    float* __restrict__ out)
{
    const int tid = threadIdx.x;
    const int img = blockIdx.x >> 8;        // 256 blocks per image
    const int rp  = blockIdx.x & 255;       // row pair
    const int y   = rp*2 + (tid >> 7);
    const int x0  = (tid & 127) * 4;

    const float* P = A + img*N_PIX;
    const float* Q = A + (8 + img)*N_PIX;

    float p[3][6], q[3][6];
    #pragma unroll
    for (int dy = 0; dy < 3; ++dy) {
        int gy = y + dy - 1;
        if ((unsigned)gy < 512u) {
            const float* rowP = P + gy*512 + x0;
            const float* rowQ = Q + gy*512 + x0;
            float4 bp = *(const float4*)rowP;
            p[dy][1] = bp.x; p[dy][2] = bp.y; p[dy][3] = bp.z; p[dy][4] = bp.w;
            p[dy][0] = (x0 > 0)       ? rowP[-1] : 0.f;   // SAME conv zero pad
            p[dy][5] = (x0 + 4 < 512) ? rowP[4]  : 0.f;
            float4 bq = *(const float4*)rowQ;
            q[dy][1] = bq.x; q[dy][2] = bq.y; q[dy][3] = bq.z; q[dy][4] = bq.w;
            q[dy][0] = (x0 > 0)       ? rowQ[-1] : 0.f;
            q[dy][5] = (x0 + 4 < 512) ? rowQ[4]  : 0.f;
        } else {
            #pragma unroll
            for (int j = 0; j < 6; ++j) { p[dy][j] = 0.f; q[dy][j] = 0.f; }
        }
    }

    float o0 = 0.f, o1 = 0.f, o2 = 0.f, o3 = 0.f;
    #pragma unroll 4
    for (int oc = 0; oc < 32; ++oc) {
        float bias = W[576 + oc];
        float a0 = bias, a1 = bias, a2 = bias, a3 = bias;
        #pragma unroll
        for (int ky = 0; ky < 3; ++ky) {
            #pragma unroll
            for (int kx = 0; kx < 3; ++kx) {
                float wp = W[oc*9 + ky*3 + kx];
                float wq = W[288 + oc*9 + ky*3 + kx];
                a0 += wp*p[ky][kx]   + wq*q[ky][kx];
                a1 += wp*p[ky][kx+1] + wq*q[ky][kx+1];
                a2 += wp*p[ky][kx+2] + wq*q[ky][kx+2];
                a3 += wp*p[ky][kx+3] + wq*q[ky][kx+3];
            }
        }
        float s = w2[oc];
        o0 += fmaxf(a0, 0.f)*s; o1 += fmaxf(a1, 0.f)*s;
        o2 += fmaxf(a2, 0.f)*s; o3 += fmaxf(a3, 0.f)*s;
    }
    float bb = b2[0];
    *(float4*)(out + img*N_PIX + y*512 + x0) = make_float4(o0+bb, o1+bb, o2+bb, o3+bb);
}

// ---------------------------------------------------------------- launch
extern "C" void kernel_launch(void* const* d_in, const int* in_sizes, int n_in,
                              void* d_out, int out_size, void* d_ws, size_t ws_size,
                              hipStream_t stream) {
    const float* x  = (const float*)d_in[0];
    const float* w0 = (const float*)d_in[1];
    const float* b0 = (const float*)d_in[2];
    const float* w1 = (const float*)d_in[3];
    const float* b1 = (const float*)d_in[4];
    const float* w2 = (const float*)d_in[5];
    const float* b2 = (const float*)d_in[6];
    float* out = (float*)d_out;

    float* wsf = (float*)d_ws;
    float* A = wsf;                 // 16 planes (P imgs 0..7, Q imgs 8..15), 16 MB
    float* B = wsf + 16*N_PIX;      // ping-pong, 16 MB
    float* W = wsf + 32*N_PIX;      // WP[288] WQ[288] BIAS[32]

    prep_kernel<<<1, 320, 0, stream>>>(w0, b0, w1, b1, W);

    dim3 eg(8, 8, 16);
    erode8_kernel<<<eg, 256, 0, stream>>>(x, B, 1);   // steps 1..8  (reads x / -x)
    erode8_kernel<<<eg, 256, 0, stream>>>(B, A, 0);   // steps 9..16

    head_kernel<<<2048, 256, 0, stream>>>(A, W, w2, b2, out);
}

// Round 2
// 179.176 us; speedup vs baseline: 1.2795x; 1.2795x over previous
//
#include <hip/hip_runtime.h>
#include <math.h>

// SDFNet: conv1x1(1->8) -> 16x (h += minpool3(h)) -> conv3x3(8->32) -> relu -> conv1x1(32->1)
//
// Factorization: erosion steps act per-channel on affine maps of x.
//   w0[c] > 0: h_c after 16 iters = w0[c]*P16(x) + b0[c]*2^16   (P = min-iterate of x)
//   w0[c] < 0: h_c = |w0[c]|*Q16 + b0[c]*2^16, Q = min-iterate of -x (pad +inf exact)
// Head = 3x3 conv over the 2 planes (P,Q) with folded weights, plus the b0*2^16 bias
// term which only applies for IN-IMAGE taps (reference zero-pads h) -> per-oc edge
// corrections base/cl/cr derived from beta[oc,k] = 65536*sum_ic b0[ic]*w1[oc,ic,k].

#define N_PIX (512*512)
#define INF __builtin_inff()

// ---------------------------------------------------------------- prep
// W layout: WP[0..287] WQ[288..575] BETA[576..863] B1[864..895]
__global__ void prep_kernel(const float* __restrict__ w0, const float* __restrict__ b0,
                            const float* __restrict__ w1, const float* __restrict__ b1,
                            float* __restrict__ W)
{
    int tid = threadIdx.x;
    if (tid < 288) {
        int oc = tid / 9, k = tid - oc*9;
        float wp = 0.f, wq = 0.f, wb = 0.f;
        for (int ic = 0; ic < 8; ++ic) {
            float a = w0[ic];
            float w = w1[oc*72 + ic*9 + k];
            if (a > 0.f) wp += w * a;
            else         wq += w * (-a);
            wb += b0[ic] * w;
        }
        W[tid]       = wp;
        W[288 + tid] = wq;
        W[576 + tid] = 65536.0f * wb;   // bias doubles each of 16 iters
        if (k == 0) W[864 + oc] = b1[oc];
    }
}

// ---------------------------------------------------------------- erosion: all 16 steps, registers
// Block: 384 threads = 6 waves. Wave w = one 16-row band; lane L = 4 cols (float4).
// Tile 256 cols x 96 rows; valid output = central 224 x 64 (junk creeps 1 ring/step
// from tile edges; +inf beyond-image is exact). Vertical halo between waves via LDS
// (double-buffered, 1 barrier/step); horizontal via __shfl.
__global__ __launch_bounds__(384) void erode16_kernel(
    const float* __restrict__ x, float* __restrict__ A)
{
    __shared__ float4 halo[2][2][6][64];   // [parity][top0/bot1][wave][lane]
    const int tid  = threadIdx.x;
    const int lane = tid & 63;
    const int w    = tid >> 6;             // 0..5
    const int plane = blockIdx.z;          // 0..7 = P(img), 8..15 = Q(img)
    const int tx0 = blockIdx.x*224 - 16;   // {-16, 208, 432}
    const int ty0 = blockIdx.y*64  - 16;   // {-16, 48, ..., 432}

    const float* sp = x + (plane & 7)*N_PIX;
    const float sgn = (plane >= 8) ? -1.f : 1.f;

    const int colg = tx0 + lane*4;         // global col of my col 0 (mult of 4)
    const int rowbase = ty0 + w*16;

    float4 h[16];
    #pragma unroll
    for (int r = 0; r < 16; ++r) {
        int gy = rowbase + r;
        float4 v = make_float4(INF, INF, INF, INF);
        if ((unsigned)gy < 512u && (unsigned)colg < 512u) {   // float4 fully in-image
            v = *(const float4*)(sp + gy*512 + colg);
            v.x *= sgn; v.y *= sgn; v.z *= sgn; v.w *= sgn;
        }
        h[r] = v;
    }

    const float4 inf4 = make_float4(INF, INF, INF, INF);
    for (int s = 0; s < 16; ++s) {
        int par = s & 1;
        halo[par][0][w][lane] = h[0];
        halo[par][1][w][lane] = h[15];
        __syncthreads();
        float4 rowUp = (w == 0) ? inf4 : halo[par][1][w-1][lane];
        float4 rowDn = (w == 5) ? inf4 : halo[par][0][w+1][lane];

        float4 prev = rowUp;
        #pragma unroll
        for (int r = 0; r < 16; ++r) {
            float4 nx = (r < 15) ? h[r+1] : rowDn;
            float4 vm;
            vm.x = fminf(fminf(prev.x, h[r].x), nx.x);
            vm.y = fminf(fminf(prev.y, h[r].y), nx.y);
            vm.z = fminf(fminf(prev.z, h[r].z), nx.z);
            vm.w = fminf(fminf(prev.w, h[r].w), nx.w);
            float hl = __shfl_up(vm.w, 1, 64);
            float hr = __shfl_down(vm.x, 1, 64);
            if (lane == 0)  hl = INF;   // beyond tile: +inf (exact at image edge, junk zone otherwise)
            if (lane == 63) hr = INF;
            float4 m;
            m.x = fminf(fminf(hl, vm.x), vm.y);
            m.y = fminf(fminf(vm.x, vm.y), vm.z);
            m.z = fminf(fminf(vm.y, vm.z), vm.w);
            m.w = fminf(fminf(vm.z, vm.w), hr);
            prev = h[r];
            h[r].x += m.x; h[r].y += m.y; h[r].z += m.z; h[r].w += m.w;
        }
    }

    // valid: tile rows [16,80) = waves 1..4 fully; tile cols [16,240) = lanes [4,60)
    if (w >= 1 && w <= 4 && lane >= 4 && lane < 60 && (unsigned)colg < 512u) {
        float* dp = A + plane*N_PIX;
        #pragma unroll
        for (int r = 0; r < 16; ++r) {
            int gy = rowbase + r;   // guaranteed in [0,512)
            *(float4*)(dp + gy*512 + colg) = h[r];
        }
    }
}

// ---------------------------------------------------------------- head
// Wave = one full image row (64 lanes x 8 px). 3x3 conv over P,Q (zero-padded like
// reference), relu, dot w2. Bias edge-corrections base/cl/cr handle the beta terms
// exactly (reference zero-pads h, so out-of-image taps must NOT get the b0*2^16 part).
__global__ __launch_bounds__(256) void head_kernel(
    const float* __restrict__ A, const float* __restrict__ W,
    const float* __restrict__ w2, const float* __restrict__ b2,
    float* __restrict__ out)
{
    const int tid  = threadIdx.x;
    const int lane = tid & 63;
    const int w    = tid >> 6;
    const int img  = blockIdx.x >> 7;            // 128 blocks per image
    const int y    = (blockIdx.x & 127)*4 + w;   // wave-uniform row
    const int x0   = lane*8;

    const float* P = A + img*N_PIX;
    const float* Q = A + (8 + img)*N_PIX;

    float p[3][10], q[3][10], ry[3];
    #pragma unroll
    for (int dy = 0; dy < 3; ++dy) {
        int gy = y + dy - 1;
        if ((unsigned)gy < 512u) {               // wave-uniform branch
            ry[dy] = 1.f;
            const float* rp = P + gy*512 + x0;
            float4 a = *(const float4*)rp;
            float4 b = *(const float4*)(rp + 4);
            p[dy][1]=a.x; p[dy][2]=a.y; p[dy][3]=a.z; p[dy][4]=a.w;
            p[dy][5]=b.x; p[dy][6]=b.y; p[dy][7]=b.z; p[dy][8]=b.w;
            float pl = __shfl_up(b.w, 1, 64);
            float pr = __shfl_down(a.x, 1, 64);
            p[dy][0] = (lane == 0)  ? 0.f : pl;  // SAME conv zero pad
            p[dy][9] = (lane == 63) ? 0.f : pr;
            const float* rq = Q + gy*512 + x0;
            float4 c = *(const float4*)rq;
            float4 d = *(const float4*)(rq + 4);
            q[dy][1]=c.x; q[dy][2]=c.y; q[dy][3]=c.z; q[dy][4]=c.w;
            q[dy][5]=d.x; q[dy][6]=d.y; q[dy][7]=d.z; q[dy][8]=d.w;
            float ql = __shfl_up(d.w, 1, 64);
            float qr = __shfl_down(c.x, 1, 64);
            q[dy][0] = (lane == 0)  ? 0.f : ql;
            q[dy][9] = (lane == 63) ? 0.f : qr;
        } else {
            ry[dy] = 0.f;
            #pragma unroll
            for (int j = 0; j < 10; ++j) { p[dy][j] = 0.f; q[dy][j] = 0.f; }
        }
    }

    float o[8];
    #pragma unroll
    for (int j = 0; j < 8; ++j) o[j] = 0.f;

    #pragma unroll 2
    for (int oc = 0; oc < 32; ++oc) {
        // bias: b1 + sum over IN-IMAGE taps of beta[oc,k]
        float base = W[864 + oc];
        float cl = 0.f, cr = 0.f;
        #pragma unroll
        for (int ky = 0; ky < 3; ++ky) {
            float b0k = W[576 + oc*9 + ky*3 + 0];
            float b1k = W[576 + oc*9 + ky*3 + 1];
            float b2k = W[576 + oc*9 + ky*3 + 2];
            base += ry[ky] * (b0k + b1k + b2k);
            cl   += ry[ky] * b0k;     // tap kx=0 is oob only for px x=0 (lane0,j=0)
            cr   += ry[ky] * b2k;     // tap kx=2 is oob only for px x=511 (lane63,j=7)
        }
        float acc[8];
        #pragma unroll
        for (int j = 0; j < 8; ++j) acc[j] = base;
        if (lane == 0)  acc[0] -= cl;
        if (lane == 63) acc[7] -= cr;

        #pragma unroll
        for (int ky = 0; ky < 3; ++ky) {
            #pragma unroll
            for (int kx = 0; kx < 3; ++kx) {
                float wp = W[oc*9 + ky*3 + kx];
                float wq = W[288 + oc*9 + ky*3 + kx];
                #pragma unroll
                for (int j = 0; j < 8; ++j)
                    acc[j] += wp*p[ky][kx+j] + wq*q[ky][kx+j];
            }
        }
        float s = w2[oc];
        #pragma unroll
        for (int j = 0; j < 8; ++j) o[j] += fmaxf(acc[j], 0.f) * s;
    }

    float bb = b2[0];
    float* op = out + img*N_PIX + y*512 + x0;
    *(float4*)(op)     = make_float4(o[0]+bb, o[1]+bb, o[2]+bb, o[3]+bb);
    *(float4*)(op + 4) = make_float4(o[4]+bb, o[5]+bb, o[6]+bb, o[7]+bb);
}

// ---------------------------------------------------------------- launch
extern "C" void kernel_launch(void* const* d_in, const int* in_sizes, int n_in,
                              void* d_out, int out_size, void* d_ws, size_t ws_size,
                              hipStream_t stream) {
    const float* x  = (const float*)d_in[0];
    const float* w0 = (const float*)d_in[1];
    const float* b0 = (const float*)d_in[2];
    const float* w1 = (const float*)d_in[3];
    const float* b1 = (const float*)d_in[4];
    const float* w2 = (const float*)d_in[5];
    const float* b2 = (const float*)d_in[6];
    float* out = (float*)d_out;

    float* wsf = (float*)d_ws;
    float* A = wsf;                 // 16 planes (P imgs 0..7, Q imgs 8..15), 16.8 MB
    float* W = wsf + 16*N_PIX;      // 896 floats of folded weights

    prep_kernel<<<1, 320, 0, stream>>>(w0, b0, w1, b1, W);

    dim3 eg(3, 8, 16);
    erode16_kernel<<<eg, 384, 0, stream>>>(x, A);

    head_kernel<<<1024, 256, 0, stream>>>(A, W, w2, b2, out);
}

// Round 3
// 161.796 us; speedup vs baseline: 1.4169x; 1.1074x over previous
//
#include <hip/hip_runtime.h>
#include <math.h>

// SDFNet: conv1x1(1->8) -> 16x (h += minpool3(h)) -> conv3x3(8->32) -> relu -> conv1x1(32->1)
//
// Factorization: erosion steps act per-channel on affine maps of x.
//   w0[c] > 0: h_c after 16 iters = w0[c]*P16(x) + b0[c]*2^16   (P = min-iterate of x)
//   w0[c] < 0: h_c = |w0[c]|*Q16 + b0[c]*2^16, Q = min-iterate of -x (pad +inf exact)
// Head = 3x3 conv over (P,Q) with folded weights WPQ (interleaved for packed fp32 FMA),
// plus beta = 65536*sum_ic b0*w1 applied only for in-image taps (ref zero-pads h).

#define N_PIX (512*512)
#define INF __builtin_inff()

typedef __attribute__((ext_vector_type(2))) float f2;

// ---------------------------------------------------------------- prep
// W layout: WPQ interleaved [oc*18 + k*2 + {0:wp,1:wq}] (0..575),
//           BETA [576 + oc*9 + k] (576..863), B1 [864 + oc] (864..895)
__global__ void prep_kernel(const float* __restrict__ w0, const float* __restrict__ b0,
                            const float* __restrict__ w1, const float* __restrict__ b1,
                            float* __restrict__ W)
{
    int tid = threadIdx.x;
    if (tid < 288) {
        int oc = tid / 9, k = tid - oc*9;
        float wp = 0.f, wq = 0.f, wb = 0.f;
        for (int ic = 0; ic < 8; ++ic) {
            float a = w0[ic];
            float w = w1[oc*72 + ic*9 + k];
            if (a > 0.f) wp += w * a;
            else         wq += w * (-a);
            wb += b0[ic] * w;
        }
        W[oc*18 + k*2 + 0] = wp;
        W[oc*18 + k*2 + 1] = wq;
        W[576 + oc*9 + k]  = 65536.0f * wb;   // bias doubles each of 16 iters
        if (k == 0) W[864 + oc] = b1[oc];
    }
}

// ---------------------------------------------------------------- erosion: all 16 steps
// Block 384 = 6 waves x 16 rows; lane = 4 cols (float4). Tile 256x96, valid central
// 224x64 (junk creeps 1 ring/step from tile edges; +inf beyond image is exact).
// 2 steps per LDS halo exchange -> 8 barriers total.
__device__ __forceinline__ float4 row_update(float4 a, float4 b, float4 c, int lane) {
    float4 vm;
    vm.x = fminf(fminf(a.x, b.x), c.x);
    vm.y = fminf(fminf(a.y, b.y), c.y);
    vm.z = fminf(fminf(a.z, b.z), c.z);
    vm.w = fminf(fminf(a.w, b.w), c.w);
    float hl = __shfl_up(vm.w, 1, 64);
    float hr = __shfl_down(vm.x, 1, 64);
    if (lane == 0)  hl = INF;   // beyond tile: +inf (exact at image edge, junk zone otherwise)
    if (lane == 63) hr = INF;
    float4 o;
    o.x = b.x + fminf(fminf(hl, vm.x), vm.y);
    o.y = b.y + fminf(fminf(vm.x, vm.y), vm.z);
    o.z = b.z + fminf(fminf(vm.y, vm.z), vm.w);
    o.w = b.w + fminf(fminf(vm.z, vm.w), hr);
    return o;
}

__global__ __launch_bounds__(384) void erode16_kernel(
    const float* __restrict__ x, float* __restrict__ A)
{
    __shared__ float4 halo[2][6][4][64];   // [parity][band][row0,row1,row14,row15][lane]
    const int tid  = threadIdx.x;
    const int lane = tid & 63;
    const int w    = tid >> 6;             // band 0..5
    const int plane = blockIdx.z;          // 0..7 = P(img), 8..15 = Q(img)
    const int tx0 = blockIdx.x*224 - 16;
    const int ty0 = blockIdx.y*64  - 16;

    const float* sp = x + (plane & 7)*N_PIX;
    const float sgn = (plane >= 8) ? -1.f : 1.f;

    const int colg = tx0 + lane*4;
    const int rowbase = ty0 + w*16;

    float4 h[16];
    #pragma unroll
    for (int r = 0; r < 16; ++r) {
        int gy = rowbase + r;
        float4 v = make_float4(INF, INF, INF, INF);
        if ((unsigned)gy < 512u && (unsigned)colg < 512u) {
            v = *(const float4*)(sp + gy*512 + colg);
            v.x *= sgn; v.y *= sgn; v.z *= sgn; v.w *= sgn;
        }
        h[r] = v;
    }

    const float4 inf4 = make_float4(INF, INF, INF, INF);
    for (int s = 0; s < 8; ++s) {          // 8 pairs = 16 steps
        int par = s & 1;
        halo[par][w][0][lane] = h[0];
        halo[par][w][1][lane] = h[1];
        halo[par][w][2][lane] = h[14];
        halo[par][w][3][lane] = h[15];
        __syncthreads();
        float4 up0 = (w == 0) ? inf4 : halo[par][w-1][2][lane];   // row -2
        float4 up1 = (w == 0) ? inf4 : halo[par][w-1][3][lane];   // row -1
        float4 dn0 = (w == 5) ? inf4 : halo[par][w+1][0][lane];   // row 16
        float4 dn1 = (w == 5) ? inf4 : halo[par][w+1][1][lane];   // row 17

        // step A: rows -1..16 (18 updates)
        float4 hup = row_update(up0, up1, h[0], lane);
        float4 hdn = row_update(h[15], dn0, dn1, lane);
        float4 prev = up1;
        #pragma unroll
        for (int r = 0; r < 16; ++r) {
            float4 nx = (r < 15) ? h[r+1] : dn0;
            float4 nb = row_update(prev, h[r], nx, lane);
            prev = h[r];
            h[r] = nb;
        }
        // step B: rows 0..15 (16 updates)
        prev = hup;
        #pragma unroll
        for (int r = 0; r < 16; ++r) {
            float4 nx = (r < 15) ? h[r+1] : hdn;
            float4 nb = row_update(prev, h[r], nx, lane);
            prev = h[r];
            h[r] = nb;
        }
    }

    // valid: waves 1..4, lanes 4..59, in-image cols
    if (w >= 1 && w <= 4 && lane >= 4 && lane < 60 && (unsigned)colg < 512u) {
        float* dp = A + plane*N_PIX;
        #pragma unroll
        for (int r = 0; r < 16; ++r) {
            int gy = rowbase + r;
            *(float4*)(dp + gy*512 + colg) = h[r];
        }
    }
}

// ---------------------------------------------------------------- head
// Wave = one image row (64 lanes x 8 px). (P,Q) packed as float2 -> v_pk_fma_f32.
// Weights staged in LDS; per-wave ry-folded bias/edge corrections precomputed.
__global__ __launch_bounds__(256) void head_kernel(
    const float* __restrict__ A, const float* __restrict__ W,
    const float* __restrict__ w2, const float* __restrict__ b2,
    float* __restrict__ out)
{
    __shared__ float Wl[896];
    __shared__ float w2l[32];
    __shared__ float Bb[4][32], Bcl[4][32], Bcr[4][32];

    const int tid  = threadIdx.x;
    const int lane = tid & 63;
    const int w    = tid >> 6;
    const int img  = blockIdx.x >> 7;            // 128 blocks per image
    const int y    = (blockIdx.x & 127)*4 + w;   // wave-uniform row
    const int x0   = lane*8;

    for (int i = tid; i < 896; i += 256) Wl[i] = W[i];
    if (tid < 32) w2l[tid] = w2[tid];
    __syncthreads();

    // per-wave fold of beta into base/cl/cr (ry is wave-uniform)
    float ry0 = (y >= 1)   ? 1.f : 0.f;
    float ry2 = (y <= 510) ? 1.f : 0.f;
    if (lane < 32) {
        int oc = lane;
        float base = Wl[864 + oc], cl = 0.f, cr = 0.f;
        float ry[3] = {ry0, 1.f, ry2};
        #pragma unroll
        for (int ky = 0; ky < 3; ++ky) {
            float b0k = Wl[576 + oc*9 + ky*3 + 0];
            float b1k = Wl[576 + oc*9 + ky*3 + 1];
            float b2k = Wl[576 + oc*9 + ky*3 + 2];
            base += ry[ky] * (b0k + b1k + b2k);
            cl   += ry[ky] * b0k;     // oob only at px x=0
            cr   += ry[ky] * b2k;     // oob only at px x=511
        }
        Bb[w][oc] = base; Bcl[w][oc] = cl; Bcr[w][oc] = cr;
    }
    // intra-wave LDS producer/consumer: no block barrier needed (lgkmcnt ordering)

    const float* P = A + img*N_PIX;
    const float* Q = A + (8 + img)*N_PIX;

    f2 pq[3][10];
    #pragma unroll
    for (int dy = 0; dy < 3; ++dy) {
        int gy = y + dy - 1;
        if ((unsigned)gy < 512u) {               // wave-uniform branch
            const float* rp = P + gy*512 + x0;
            const float* rq = Q + gy*512 + x0;
            float4 a = *(const float4*)rp;
            float4 b = *(const float4*)(rp + 4);
            float4 c = *(const float4*)rq;
            float4 d = *(const float4*)(rq + 4);
            pq[dy][1] = (f2){a.x, c.x}; pq[dy][2] = (f2){a.y, c.y};
            pq[dy][3] = (f2){a.z, c.z}; pq[dy][4] = (f2){a.w, c.w};
            pq[dy][5] = (f2){b.x, d.x}; pq[dy][6] = (f2){b.y, d.y};
            pq[dy][7] = (f2){b.z, d.z}; pq[dy][8] = (f2){b.w, d.w};
            float pl = __shfl_up(b.w, 1, 64),  ql = __shfl_up(d.w, 1, 64);
            float pr = __shfl_down(a.x, 1, 64), qr = __shfl_down(c.x, 1, 64);
            pq[dy][0] = (lane == 0)  ? (f2){0.f, 0.f} : (f2){pl, ql};   // SAME zero pad
            pq[dy][9] = (lane == 63) ? (f2){0.f, 0.f} : (f2){pr, qr};
        } else {
            #pragma unroll
            for (int j = 0; j < 10; ++j) pq[dy][j] = (f2){0.f, 0.f};
        }
    }

    float o[8];
    #pragma unroll
    for (int j = 0; j < 8; ++j) o[j] = 0.f;

    const f2* Wv = (const f2*)Wl;   // Wv[oc*9 + k] = {wp, wq}
    for (int oc = 0; oc < 32; ++oc) {
        f2 acc[8];
        f2 w0v = Wv[oc*9 + 0];
        #pragma unroll
        for (int j = 0; j < 8; ++j) acc[j] = w0v * pq[0][j];
        #pragma unroll
        for (int t = 1; t < 9; ++t) {
            const int ky = t / 3, kx = t - ky*3;
            f2 wv = Wv[oc*9 + t];
            #pragma unroll
            for (int j = 0; j < 8; ++j) acc[j] += wv * pq[ky][kx + j];
        }
        float base = Bb[w][oc], sc = w2l[oc];
        float s[8];
        #pragma unroll
        for (int j = 0; j < 8; ++j) s[j] = acc[j].x + acc[j].y + base;
        if (lane == 0)  s[0] -= Bcl[w][oc];
        if (lane == 63) s[7] -= Bcr[w][oc];
        #pragma unroll
        for (int j = 0; j < 8; ++j) o[j] += fmaxf(s[j], 0.f) * sc;
    }

    float bb = b2[0];
    float* op = out + img*N_PIX + y*512 + x0;
    *(float4*)(op)     = make_float4(o[0]+bb, o[1]+bb, o[2]+bb, o[3]+bb);
    *(float4*)(op + 4) = make_float4(o[4]+bb, o[5]+bb, o[6]+bb, o[7]+bb);
}

// ---------------------------------------------------------------- launch
extern "C" void kernel_launch(void* const* d_in, const int* in_sizes, int n_in,
                              void* d_out, int out_size, void* d_ws, size_t ws_size,
                              hipStream_t stream) {
    const float* x  = (const float*)d_in[0];
    const float* w0 = (const float*)d_in[1];
    const float* b0 = (const float*)d_in[2];
    const float* w1 = (const float*)d_in[3];
    const float* b1 = (const float*)d_in[4];
    const float* w2 = (const float*)d_in[5];
    const float* b2 = (const float*)d_in[6];
    float* out = (float*)d_out;

    float* wsf = (float*)d_ws;
    float* A = wsf;                 // 16 planes (P imgs 0..7, Q imgs 8..15), 16.8 MB
    float* W = wsf + 16*N_PIX;      // 896 floats of folded weights

    prep_kernel<<<1, 320, 0, stream>>>(w0, b0, w1, b1, W);

    dim3 eg(3, 8, 16);
    erode16_kernel<<<eg, 384, 0, stream>>>(x, A);

    head_kernel<<<1024, 256, 0, stream>>>(A, W, w2, b2, out);
}